// Round 4
// baseline (522.823 us; speedup 1.0000x reference)
//
#include <hip/hip_runtime.h>
#include <math.h>

#define HH    48
#define CFEAT 512
#define HID   256
#define NPOS  (HH*HH)   // 2304
#define TQ    32        // queries per block
#define NEV   128       // evals per block = TQ*4
#define ACTP  264       // padded act row (bf16): 528B stride, rows 16B-aligned

typedef __attribute__((ext_vector_type(8))) short bf16x8;
typedef __attribute__((ext_vector_type(4))) float f32x4;

static __device__ __forceinline__ unsigned short f2bf(float x) {
  unsigned int u = __float_as_uint(x);
  u += 0x7fffu + ((u >> 16) & 1u);     // RNE
  return (unsigned short)(u >> 16);
}
static __device__ __forceinline__ float bf2f(unsigned short h) {
  return __uint_as_float(((unsigned int)h) << 16);
}

// ---------------------------------------------------------------------------
// Kernel 1: P[b][pos][n] = b0[n] + sum_c feat[b][c][pos] * W0[c][n]  (fp32)
// ---------------------------------------------------------------------------
__global__ __launch_bounds__(256) void liif_precompute(
    const float* __restrict__ feat, const float* __restrict__ W0,
    const float* __restrict__ b0, float* __restrict__ P)
{
  int blk = blockIdx.x;                 // 0..1151
  int b   = blk / (NPOS/4);
  int p0  = (blk - b*(NPOS/4)) * 4;
  int n   = threadIdx.x;
  const float* f = feat + (size_t)b * CFEAT * NPOS + p0;
  float bias = b0[n];
  float a0 = bias, a1 = bias, a2 = bias, a3 = bias;
  #pragma unroll 4
  for (int c = 0; c < CFEAT; ++c) {
    float w = W0[c*HID + n];
    const float* fr = f + (size_t)c * NPOS;
    a0 += fr[0]*w; a1 += fr[1]*w; a2 += fr[2]*w; a3 += fr[3]*w;
  }
  float* Pp = P + ((size_t)b*NPOS + p0)*HID + n;
  Pp[0*HID] = a0; Pp[1*HID] = a1; Pp[2*HID] = a2; Pp[3*HID] = a3;
}

// ---------------------------------------------------------------------------
// Kernel 2: transpose+convert W1..W3 -> bf16 Wt[l][n][k]; W4 -> f32 W4t[o][k]
// ---------------------------------------------------------------------------
__global__ __launch_bounds__(256) void liif_convert(
    const float* __restrict__ W1, const float* __restrict__ W2,
    const float* __restrict__ W3, const float* __restrict__ W4,
    unsigned short* __restrict__ wt, float* __restrict__ w4t)
{
  int b = blockIdx.x, t = threadIdx.x;
  if (b < 768) {
    int l = b >> 8, n = b & 255;
    const float* W = (l == 0) ? W1 : (l == 1) ? W2 : W3;
    wt[l*65536 + n*256 + t] = f2bf(W[t*256 + n]);   // Wt[n][k] = W[k][n]
  } else {
    for (int o = 0; o < 3; ++o) w4t[o*256 + t] = W4[t*3 + o];
  }
}

// ---------------------------------------------------------------------------
// Kernel 3: fused main. 128 evals/block, 8 waves; wave = 128x32 output slice.
// Weights live in REGISTERS (16 bf16x8 frags/wave/layer), double-set prefetch.
// MFMA operands swapped: A = W-frag (regs), B = act-frag (LDS) -> D[n][m],
// giving contiguous-n packed b64 writeback.
// ---------------------------------------------------------------------------

// load wave's 32x256 W-slice as a-operand frags: DST[nt*8+kc], nt<2, kc<8
#define PREFETCH(DST, WSRC) do {                                              \
    _Pragma("unroll")                                                         \
    for (int nt_ = 0; nt_ < 2; ++nt_) {                                       \
      _Pragma("unroll")                                                       \
      for (int kc_ = 0; kc_ < 8; ++kc_) {                                     \
        DST[nt_*8 + kc_] = *(const bf16x8*)&(WSRC)[                           \
            (size_t)(nW + nt_*16 + lr)*256 + kc_*32 + lk*8];                  \
      }                                                                       \
    }                                                                         \
  } while (0)

#define LAYER(BSET, BIAS) do {                                                \
    f32x4 acc[16];                                                            \
    _Pragma("unroll")                                                         \
    for (int i_ = 0; i_ < 16; ++i_) acc[i_] = (f32x4){0.f, 0.f, 0.f, 0.f};    \
    _Pragma("unroll")                                                         \
    for (int kc_ = 0; kc_ < 8; ++kc_) {                                       \
      _Pragma("unroll")                                                       \
      for (int mt_ = 0; mt_ < 8; ++mt_) {                                     \
        bf16x8 af_ = *(const bf16x8*)&act[(mt_*16 + lr)*ACTP + kc_*32 + lk*8];\
        acc[mt_]     = __builtin_amdgcn_mfma_f32_16x16x32_bf16(               \
            BSET[kc_],     af_, acc[mt_],     0, 0, 0);                       \
        acc[8 + mt_] = __builtin_amdgcn_mfma_f32_16x16x32_bf16(               \
            BSET[8 + kc_], af_, acc[8 + mt_], 0, 0, 0);                       \
      }                                                                       \
    }                                                                         \
    __syncthreads();  /* all act reads of this layer done */                  \
    {                                                                         \
      f32x4 bv0_ = *(const f32x4*)&(BIAS)[nW + lk*4];                         \
      f32x4 bv1_ = *(const f32x4*)&(BIAS)[nW + 16 + lk*4];                    \
      _Pragma("unroll")                                                       \
      for (int mt_ = 0; mt_ < 8; ++mt_) {                                     \
        f32x4 a0_ = acc[mt_], a1_ = acc[8 + mt_];                             \
        unsigned int l0_ = (unsigned int)f2bf(fmaxf(a0_[0] + bv0_[0], 0.f))   \
                         | ((unsigned int)f2bf(fmaxf(a0_[1] + bv0_[1], 0.f)) << 16); \
        unsigned int h0_ = (unsigned int)f2bf(fmaxf(a0_[2] + bv0_[2], 0.f))   \
                         | ((unsigned int)f2bf(fmaxf(a0_[3] + bv0_[3], 0.f)) << 16); \
        unsigned int l1_ = (unsigned int)f2bf(fmaxf(a1_[0] + bv1_[0], 0.f))   \
                         | ((unsigned int)f2bf(fmaxf(a1_[1] + bv1_[1], 0.f)) << 16); \
        unsigned int h1_ = (unsigned int)f2bf(fmaxf(a1_[2] + bv1_[2], 0.f))   \
                         | ((unsigned int)f2bf(fmaxf(a1_[3] + bv1_[3], 0.f)) << 16); \
        uint2* p0_ = (uint2*)&act[(mt_*16 + lr)*ACTP + nW + lk*4];            \
        uint2* p1_ = (uint2*)&act[(mt_*16 + lr)*ACTP + nW + 16 + lk*4];       \
        *p0_ = make_uint2(l0_, h0_);                                          \
        *p1_ = make_uint2(l1_, h1_);                                          \
      }                                                                       \
    }                                                                         \
    __syncthreads();  /* writeback visible before next layer's reads */      \
  } while (0)

__global__ __launch_bounds__(512, 2) void liif_main(
    const float* __restrict__ coord, const float* __restrict__ cell,
    const float* __restrict__ P,  const float* __restrict__ W0,
    const unsigned short* __restrict__ wt,
    const float* __restrict__ b1, const float* __restrict__ b2,
    const float* __restrict__ b3, const float* __restrict__ b4,
    const float* __restrict__ w4t, float* __restrict__ out)
{
  __shared__ __align__(16) unsigned short act[NEV*ACTP];   // 67.6 KB
  __shared__ int   lin_s[NEV];
  __shared__ float r0_s[NEV], r1_s[NEV], rc0_s[NEV], rc1_s[NEV], area_s[NEV];
  __shared__ float pred_s[NEV][3];

  const int t   = threadIdx.x;
  const int blk = blockIdx.x;
  const int b   = blk >> 11;            // 2048 blocks per batch
  const int q0  = (blk & 2047) * TQ;

  const int lane = t & 63;
  const int w    = t >> 6;              // 0..7
  const int nW   = w * 32;              // wave's output-col slice base
  const int lr   = lane & 15;
  const int lk   = lane >> 4;

  // W-frag register sets (64 VGPR each); L1 uses bA, L2 bB, L3 bA (reloaded)
  bf16x8 bA[16], bB[16];
  PREFETCH(bA, wt);                     // W1 — issued first, hidden by A/B

  // ---- Phase A: indices, rel coords, areas (bit-exact vs numpy fp32) ------
  if (t < NEV) {
    const int e = t;
    const int q = q0 + (e >> 2);
    const int s = e & 3;                // [(-1,-1),(-1,1),(1,-1),(1,1)]
    const size_t cbase = (((size_t)b << 16) + q) * 2;
    float c0 = coord[cbase + 0];
    float c1 = coord[cbase + 1];
    float vx = (s & 2) ? 1.0f : -1.0f;
    float vy = (s & 1) ? 1.0f : -1.0f;
    const float RXY = (float)(1.0/48.0);
    const float CLO = (float)(-1.0 + 1e-6);
    const float CHI = (float)( 1.0 - 1e-6);
    float gx = __fadd_rn(c0, __fadd_rn(__fmul_rn(vx, RXY), 1e-6f));
    float gy = __fadd_rn(c1, __fadd_rn(__fmul_rn(vy, RXY), 1e-6f));
    gx = fminf(fmaxf(gx, CLO), CHI);
    gy = fminf(fmaxf(gy, CLO), CHI);
    float xr = __fmul_rn(__fsub_rn(__fmul_rn(__fadd_rn(gx, 1.0f), 48.0f), 1.0f), 0.5f);
    float xc = __fmul_rn(__fsub_rn(__fmul_rn(__fadd_rn(gy, 1.0f), 48.0f), 1.0f), 0.5f);
    int ir = (int)rintf(xr); ir = ir < 0 ? 0 : (ir > HH-1 ? HH-1 : ir);
    int ic = (int)rintf(xc); ic = ic < 0 ? 0 : (ic > HH-1 ? HH-1 : ic);
    lin_s[e] = ir*HH + ic;
    const float T2 = (float)(2.0/48.0);
    float qcr = __fsub_rn(__fmul_rn(__fadd_rn((float)ir, 0.5f), T2), 1.0f);
    float qcc = __fsub_rn(__fmul_rn(__fadd_rn((float)ic, 0.5f), T2), 1.0f);
    float r0 = __fmul_rn(__fsub_rn(c0, qcr), 48.0f);
    float r1 = __fmul_rn(__fsub_rn(c1, qcc), 48.0f);
    r0_s[e] = r0; r1_s[e] = r1;
    area_s[e] = __fadd_rn(fabsf(__fmul_rn(r0, r1)), 1e-9f);
    rc0_s[e] = __fmul_rn(cell[cbase + 0], 48.0f);
    rc1_s[e] = __fmul_rn(cell[cbase + 1], 48.0f);
  }
  __syncthreads();

  // ---- Phase B: h0 -> bf16 act. 512 thr: 128 col-pairs x 4 row-quarters ---
  {
    const int c2 = (t & 127) * 2;       // column pair
    const int rq = t >> 7;              // row quarter
    float wA = W0[(size_t)512*HID + c2],  wBv = W0[(size_t)512*HID + c2 + 1];
    float xA = W0[(size_t)513*HID + c2],  xB = W0[(size_t)513*HID + c2 + 1];
    float yA = W0[(size_t)514*HID + c2],  yB = W0[(size_t)514*HID + c2 + 1];
    float zA = W0[(size_t)515*HID + c2],  zB = W0[(size_t)515*HID + c2 + 1];
    const float* Pb = P + (size_t)b * NPOS * HID;
    #pragma unroll 4
    for (int i = 0; i < 32; ++i) {
      const int e = rq*32 + i;
      const float* pr = Pb + (size_t)lin_s[e]*HID + c2;
      float vA = pr[0] + r0_s[e]*wA + r1_s[e]*xA + rc0_s[e]*yA + rc1_s[e]*zA;
      float vB = pr[1] + r0_s[e]*wBv + r1_s[e]*xB + rc0_s[e]*yB + rc1_s[e]*zB;
      unsigned int pk = (unsigned int)f2bf(fmaxf(vA, 0.0f)) |
                        ((unsigned int)f2bf(fmaxf(vB, 0.0f)) << 16);
      *(unsigned int*)&act[e*ACTP + c2] = pk;
    }
  }

  PREFETCH(bB, wt + 65536);             // W2 — hidden under layer 1
  __syncthreads();                      // act (h0) ready

  LAYER(bA, b1);                        // layer 1
  PREFETCH(bA, wt + 2*65536);           // W3 — hidden under layer 2
  LAYER(bB, b2);                        // layer 2
  LAYER(bA, b3);                        // layer 3
  // LAYER ends with a barrier -> act final, visible to all

  // ---- Phase D: final 256->3 layer (uniform w4t broadcast per wave) -------
  if (t < NEV) {
    const int e = t;
    float a0 = b4[0], a1 = b4[1], a2 = b4[2];
    #pragma unroll 4
    for (int k = 0; k < HID; k += 8) {
      bf16x8 av = *(const bf16x8*)&act[e*ACTP + k];
      #pragma unroll
      for (int i = 0; i < 8; ++i) {
        float v = bf2f((unsigned short)av[i]);
        a0 += v * w4t[k + i];
        a1 += v * w4t[256 + k + i];
        a2 += v * w4t[512 + k + i];
      }
    }
    pred_s[e][0] = a0; pred_s[e][1] = a1; pred_s[e][2] = a2;
  }
  __syncthreads();

  // ---- blend: w[s] = area[3-s]/tot ---------------------------------------
  if (t < TQ*3) {
    const int q = t / 3, o = t - (t/3)*3;
    const int eb = q*4;
    float a0 = area_s[eb+0], a1 = area_s[eb+1], a2 = area_s[eb+2], a3 = area_s[eb+3];
    float tot = ((a0 + a1) + a2) + a3;
    float rv = (pred_s[eb+0][o]*a3 + pred_s[eb+1][o]*a2 +
                pred_s[eb+2][o]*a1 + pred_s[eb+3][o]*a0) / tot;
    out[(((size_t)b << 16) + (q0 + q))*3 + o] = rv;
  }
}

// ---------------------------------------------------------------------------
extern "C" void kernel_launch(void* const* d_in, const int* in_sizes, int n_in,
                              void* d_out, int out_size, void* d_ws, size_t ws_size,
                              hipStream_t stream)
{
  const float* feat  = (const float*)d_in[0];
  const float* coord = (const float*)d_in[1];
  const float* cell  = (const float*)d_in[2];
  const float* W0    = (const float*)d_in[3];
  const float* b0    = (const float*)d_in[4];
  const float* W1    = (const float*)d_in[5];
  const float* b1    = (const float*)d_in[6];
  const float* W2    = (const float*)d_in[7];
  const float* b2    = (const float*)d_in[8];
  const float* W3    = (const float*)d_in[9];
  const float* b3    = (const float*)d_in[10];
  const float* W4    = (const float*)d_in[11];
  const float* b4    = (const float*)d_in[12];
  float* outp = (float*)d_out;

  // ws layout: P f32 [2*2304*256] = 4,718,592 B | Wt bf16 3*64K = 393,216 B
  //            | W4t f32 3*256 = 3,072 B
  float*          P    = (float*)d_ws;
  unsigned short* wtp  = (unsigned short*)((char*)d_ws + 4718592);
  float*          w4tp = (float*)((char*)d_ws + 4718592 + 393216);

  hipLaunchKernelGGL(liif_precompute, dim3(2*(NPOS/4)), dim3(256), 0, stream,
                     feat, W0, b0, P);
  hipLaunchKernelGGL(liif_convert, dim3(769), dim3(256), 0, stream,
                     W1, W2, W3, W4, wtp, w4tp);
  hipLaunchKernelGGL(liif_main, dim3(4096), dim3(512), 0, stream,
                     coord, cell, P, W0, wtp, b1, b2, b3, b4, w4tp, outp);
}

// Round 5
// 370.180 us; speedup vs baseline: 1.4123x; 1.4123x over previous
//
#include <hip/hip_runtime.h>
#include <math.h>

#define HH    48
#define CFEAT 512
#define HID   256
#define NPOS  (HH*HH)   // 2304
#define TQ    32        // queries per block
#define NEV   128       // evals per block = TQ*4
#define ACTP  264       // padded act row (bf16): 528B stride, rows 16B-aligned

typedef __attribute__((ext_vector_type(8))) short bf16x8;
typedef __attribute__((ext_vector_type(4))) float f32x4;

static __device__ __forceinline__ unsigned short f2bf(float x) {
  unsigned int u = __float_as_uint(x);
  u += 0x7fffu + ((u >> 16) & 1u);     // RNE
  return (unsigned short)(u >> 16);
}
static __device__ __forceinline__ float bf2f(unsigned short h) {
  return __uint_as_float(((unsigned int)h) << 16);
}

// ---------------------------------------------------------------------------
// Kernel 1: P[b][pos][n] = b0[n] + sum_c feat[b][c][pos] * W0[c][n]  (fp32)
// ---------------------------------------------------------------------------
__global__ __launch_bounds__(256) void liif_precompute(
    const float* __restrict__ feat, const float* __restrict__ W0,
    const float* __restrict__ b0, float* __restrict__ P)
{
  int blk = blockIdx.x;                 // 0..1151
  int b   = blk / (NPOS/4);
  int p0  = (blk - b*(NPOS/4)) * 4;
  int n   = threadIdx.x;
  const float* f = feat + (size_t)b * CFEAT * NPOS + p0;
  float bias = b0[n];
  float a0 = bias, a1 = bias, a2 = bias, a3 = bias;
  #pragma unroll 4
  for (int c = 0; c < CFEAT; ++c) {
    float w = W0[c*HID + n];
    const float* fr = f + (size_t)c * NPOS;
    a0 += fr[0]*w; a1 += fr[1]*w; a2 += fr[2]*w; a3 += fr[3]*w;
  }
  float* Pp = P + ((size_t)b*NPOS + p0)*HID + n;
  Pp[0*HID] = a0; Pp[1*HID] = a1; Pp[2*HID] = a2; Pp[3*HID] = a3;
}

// ---------------------------------------------------------------------------
// Kernel 2: transpose+convert W1..W3 -> bf16 Wt[l][n][k]; W4 -> f32 W4t[o][k]
// ---------------------------------------------------------------------------
__global__ __launch_bounds__(256) void liif_convert(
    const float* __restrict__ W1, const float* __restrict__ W2,
    const float* __restrict__ W3, const float* __restrict__ W4,
    unsigned short* __restrict__ wt, float* __restrict__ w4t)
{
  int b = blockIdx.x, t = threadIdx.x;
  if (b < 768) {
    int l = b >> 8, n = b & 255;
    const float* W = (l == 0) ? W1 : (l == 1) ? W2 : W3;
    wt[l*65536 + n*256 + t] = f2bf(W[t*256 + n]);   // Wt[n][k] = W[k][n]
  } else {
    for (int o = 0; o < 3; ++o) w4t[o*256 + t] = W4[t*3 + o];
  }
}

// ---------------------------------------------------------------------------
// Kernel 3: fused main. 128 evals/block, 8 waves; wave = 128x32 output slice.
// W streamed from L2 with depth-2 named-register double buffer (short live
// ranges -> regalloc can't sink); act from LDS; 2 blocks/CU via 128-VGPR cap.
// ---------------------------------------------------------------------------

// W-fragment load: A-operand frag for swapped MFMA (n = nW + NT*16 + lr)
#define LDW(PTR, KC, NT) \
  (*(const bf16x8*)&(PTR)[(size_t)(nW + (NT)*16 + lr)*256 + (KC)*32 + lk*8])

#define LAYER(WCUR, WNXT, BIAS, DONEXT) do {                                  \
    f32x4 acc[16];                                                            \
    _Pragma("unroll")                                                         \
    for (int i_ = 0; i_ < 16; ++i_) acc[i_] = (f32x4){0.f, 0.f, 0.f, 0.f};    \
    bf16x8 cEA = nf0a, cEB = nf0b, cOA = nf1a, cOB = nf1b;                    \
    _Pragma("unroll")                                                         \
    for (int kc_ = 0; kc_ < 8; ++kc_) {                                       \
      bf16x8 wa_ = (kc_ & 1) ? cOA : cEA;                                     \
      bf16x8 wb_ = (kc_ & 1) ? cOB : cEB;                                     \
      if (kc_ < 6) {              /* depth-2 stream within layer */           \
        if (kc_ & 1) { cOA = LDW(WCUR, kc_+2, 0); cOB = LDW(WCUR, kc_+2, 1); }\
        else         { cEA = LDW(WCUR, kc_+2, 0); cEB = LDW(WCUR, kc_+2, 1); }\
      } else if (DONEXT) {        /* cross-layer prefetch (kc 6,7) */         \
        if (kc_ == 6) { nf0a = LDW(WNXT, 0, 0); nf0b = LDW(WNXT, 0, 1); }     \
        else          { nf1a = LDW(WNXT, 1, 0); nf1b = LDW(WNXT, 1, 1); }     \
      }                                                                       \
      _Pragma("unroll")                                                       \
      for (int mt_ = 0; mt_ < 8; ++mt_) {                                     \
        bf16x8 af_ = *(const bf16x8*)&act[(mt_*16 + lr)*ACTP + kc_*32 + lk*8];\
        acc[mt_]     = __builtin_amdgcn_mfma_f32_16x16x32_bf16(               \
            wa_, af_, acc[mt_],     0, 0, 0);                                 \
        acc[8 + mt_] = __builtin_amdgcn_mfma_f32_16x16x32_bf16(               \
            wb_, af_, acc[8 + mt_], 0, 0, 0);                                 \
      }                                                                       \
    }                                                                         \
    __syncthreads();  /* all act reads of this layer done */                  \
    {                                                                         \
      f32x4 bv0_ = *(const f32x4*)&(BIAS)[nW + lk*4];                         \
      f32x4 bv1_ = *(const f32x4*)&(BIAS)[nW + 16 + lk*4];                    \
      _Pragma("unroll")                                                       \
      for (int mt_ = 0; mt_ < 8; ++mt_) {                                     \
        f32x4 a0_ = acc[mt_], a1_ = acc[8 + mt_];                             \
        unsigned int l0_ = (unsigned int)f2bf(fmaxf(a0_[0] + bv0_[0], 0.f))   \
                         | ((unsigned int)f2bf(fmaxf(a0_[1] + bv0_[1], 0.f)) << 16); \
        unsigned int h0_ = (unsigned int)f2bf(fmaxf(a0_[2] + bv0_[2], 0.f))   \
                         | ((unsigned int)f2bf(fmaxf(a0_[3] + bv0_[3], 0.f)) << 16); \
        unsigned int l1_ = (unsigned int)f2bf(fmaxf(a1_[0] + bv1_[0], 0.f))   \
                         | ((unsigned int)f2bf(fmaxf(a1_[1] + bv1_[1], 0.f)) << 16); \
        unsigned int h1_ = (unsigned int)f2bf(fmaxf(a1_[2] + bv1_[2], 0.f))   \
                         | ((unsigned int)f2bf(fmaxf(a1_[3] + bv1_[3], 0.f)) << 16); \
        *(uint2*)&act[(mt_*16 + lr)*ACTP + nW + lk*4]      = make_uint2(l0_, h0_); \
        *(uint2*)&act[(mt_*16 + lr)*ACTP + nW + 16 + lk*4] = make_uint2(l1_, h1_); \
      }                                                                       \
    }                                                                         \
    __syncthreads();  /* writeback visible before next layer's reads */      \
  } while (0)

__global__ __launch_bounds__(512, 4) void liif_main(
    const float* __restrict__ coord, const float* __restrict__ cell,
    const float* __restrict__ P,  const float* __restrict__ W0,
    const unsigned short* __restrict__ wt,
    const float* __restrict__ b1, const float* __restrict__ b2,
    const float* __restrict__ b3, const float* __restrict__ b4,
    const float* __restrict__ w4t, float* __restrict__ out)
{
  __shared__ __align__(16) unsigned short act[NEV*ACTP];   // 67.6 KB
  __shared__ int   lin_s[NEV];
  __shared__ float r0_s[NEV], r1_s[NEV], rc0_s[NEV], rc1_s[NEV], area_s[NEV];
  __shared__ float pred_s[NEV][3];

  const int t   = threadIdx.x;
  const int blk = blockIdx.x;
  const int b   = blk >> 11;            // 2048 blocks per batch
  const int q0  = (blk & 2047) * TQ;

  const int lane = t & 63;
  const int w    = t >> 6;              // 0..7
  const int nW   = w * 32;              // wave's output-col slice base
  const int lr   = lane & 15;
  const int lk   = lane >> 4;

  // prefetch layer-1 kc0/kc1 W-frag pairs (hidden under Phase A/B)
  bf16x8 nf0a = LDW(wt, 0, 0), nf0b = LDW(wt, 0, 1);
  bf16x8 nf1a = LDW(wt, 1, 0), nf1b = LDW(wt, 1, 1);

  // ---- Phase A: indices, rel coords, areas (bit-exact vs numpy fp32) ------
  if (t < NEV) {
    const int e = t;
    const int q = q0 + (e >> 2);
    const int s = e & 3;                // [(-1,-1),(-1,1),(1,-1),(1,1)]
    const size_t cbase = (((size_t)b << 16) + q) * 2;
    float c0 = coord[cbase + 0];
    float c1 = coord[cbase + 1];
    float vx = (s & 2) ? 1.0f : -1.0f;
    float vy = (s & 1) ? 1.0f : -1.0f;
    const float RXY = (float)(1.0/48.0);
    const float CLO = (float)(-1.0 + 1e-6);
    const float CHI = (float)( 1.0 - 1e-6);
    float gx = __fadd_rn(c0, __fadd_rn(__fmul_rn(vx, RXY), 1e-6f));
    float gy = __fadd_rn(c1, __fadd_rn(__fmul_rn(vy, RXY), 1e-6f));
    gx = fminf(fmaxf(gx, CLO), CHI);
    gy = fminf(fmaxf(gy, CLO), CHI);
    float xr = __fmul_rn(__fsub_rn(__fmul_rn(__fadd_rn(gx, 1.0f), 48.0f), 1.0f), 0.5f);
    float xc = __fmul_rn(__fsub_rn(__fmul_rn(__fadd_rn(gy, 1.0f), 48.0f), 1.0f), 0.5f);
    int ir = (int)rintf(xr); ir = ir < 0 ? 0 : (ir > HH-1 ? HH-1 : ir);
    int ic = (int)rintf(xc); ic = ic < 0 ? 0 : (ic > HH-1 ? HH-1 : ic);
    lin_s[e] = ir*HH + ic;
    const float T2 = (float)(2.0/48.0);
    float qcr = __fsub_rn(__fmul_rn(__fadd_rn((float)ir, 0.5f), T2), 1.0f);
    float qcc = __fsub_rn(__fmul_rn(__fadd_rn((float)ic, 0.5f), T2), 1.0f);
    float r0 = __fmul_rn(__fsub_rn(c0, qcr), 48.0f);
    float r1 = __fmul_rn(__fsub_rn(c1, qcc), 48.0f);
    r0_s[e] = r0; r1_s[e] = r1;
    area_s[e] = __fadd_rn(fabsf(__fmul_rn(r0, r1)), 1e-9f);
    rc0_s[e] = __fmul_rn(cell[cbase + 0], 48.0f);
    rc1_s[e] = __fmul_rn(cell[cbase + 1], 48.0f);
  }
  __syncthreads();

  // ---- Phase B: h0 -> bf16 act. 512 thr: 128 col-pairs x 4 row-quarters ---
  {
    const int c2 = (t & 127) * 2;       // column pair
    const int rq = t >> 7;              // row quarter
    float wA = W0[(size_t)512*HID + c2],  wBv = W0[(size_t)512*HID + c2 + 1];
    float xA = W0[(size_t)513*HID + c2],  xB = W0[(size_t)513*HID + c2 + 1];
    float yA = W0[(size_t)514*HID + c2],  yB = W0[(size_t)514*HID + c2 + 1];
    float zA = W0[(size_t)515*HID + c2],  zB = W0[(size_t)515*HID + c2 + 1];
    const float* Pb = P + (size_t)b * NPOS * HID;
    #pragma unroll 4
    for (int i = 0; i < 32; ++i) {
      const int e = rq*32 + i;
      const float* pr = Pb + (size_t)lin_s[e]*HID + c2;
      float vA = pr[0] + r0_s[e]*wA + r1_s[e]*xA + rc0_s[e]*yA + rc1_s[e]*zA;
      float vB = pr[1] + r0_s[e]*wBv + r1_s[e]*xB + rc0_s[e]*yB + rc1_s[e]*zB;
      unsigned int pk = (unsigned int)f2bf(fmaxf(vA, 0.0f)) |
                        ((unsigned int)f2bf(fmaxf(vB, 0.0f)) << 16);
      *(unsigned int*)&act[e*ACTP + c2] = pk;
    }
  }
  __syncthreads();                      // act (h0) ready

  LAYER(wt,             wt + 65536,   b1, 1);   // layer 1 (prefetches W2)
  LAYER(wt + 65536,     wt + 131072,  b2, 1);   // layer 2 (prefetches W3)
  LAYER(wt + 131072,    wt,           b3, 0);   // layer 3 (no prefetch)

  // ---- Phase D: final 256->3 layer (each act row read once) ---------------
  if (t < NEV) {
    const int e = t;
    float a0 = b4[0], a1 = b4[1], a2 = b4[2];
    #pragma unroll 4
    for (int k = 0; k < HID; k += 8) {
      bf16x8 av = *(const bf16x8*)&act[e*ACTP + k];
      #pragma unroll
      for (int i = 0; i < 8; ++i) {
        float v = bf2f((unsigned short)av[i]);
        a0 += v * w4t[k + i];
        a1 += v * w4t[256 + k + i];
        a2 += v * w4t[512 + k + i];
      }
    }
    pred_s[e][0] = a0; pred_s[e][1] = a1; pred_s[e][2] = a2;
  }
  __syncthreads();

  // ---- blend: w[s] = area[3-s]/tot ---------------------------------------
  if (t < TQ*3) {
    const int q = t / 3, o = t - (t/3)*3;
    const int eb = q*4;
    float a0 = area_s[eb+0], a1 = area_s[eb+1], a2 = area_s[eb+2], a3 = area_s[eb+3];
    float tot = ((a0 + a1) + a2) + a3;
    float rv = (pred_s[eb+0][o]*a3 + pred_s[eb+1][o]*a2 +
                pred_s[eb+2][o]*a1 + pred_s[eb+3][o]*a0) / tot;
    out[(((size_t)b << 16) + (q0 + q))*3 + o] = rv;
  }
}

// ---------------------------------------------------------------------------
extern "C" void kernel_launch(void* const* d_in, const int* in_sizes, int n_in,
                              void* d_out, int out_size, void* d_ws, size_t ws_size,
                              hipStream_t stream)
{
  const float* feat  = (const float*)d_in[0];
  const float* coord = (const float*)d_in[1];
  const float* cell  = (const float*)d_in[2];
  const float* W0    = (const float*)d_in[3];
  const float* b0    = (const float*)d_in[4];
  const float* W1    = (const float*)d_in[5];
  const float* b1    = (const float*)d_in[6];
  const float* W2    = (const float*)d_in[7];
  const float* b2    = (const float*)d_in[8];
  const float* W3    = (const float*)d_in[9];
  const float* b3    = (const float*)d_in[10];
  const float* W4    = (const float*)d_in[11];
  const float* b4    = (const float*)d_in[12];
  float* outp = (float*)d_out;

  // ws layout: P f32 [2*2304*256] = 4,718,592 B | Wt bf16 3*64K = 393,216 B
  //            | W4t f32 3*256 = 3,072 B
  float*          P    = (float*)d_ws;
  unsigned short* wtp  = (unsigned short*)((char*)d_ws + 4718592);
  float*          w4tp = (float*)((char*)d_ws + 4718592 + 393216);

  hipLaunchKernelGGL(liif_precompute, dim3(2*(NPOS/4)), dim3(256), 0, stream,
                     feat, W0, b0, P);
  hipLaunchKernelGGL(liif_convert, dim3(769), dim3(256), 0, stream,
                     W1, W2, W3, W4, wtp, w4tp);
  hipLaunchKernelGGL(liif_main, dim3(4096), dim3(512), 0, stream,
                     coord, cell, P, W0, wtp, b1, b2, b3, b4, w4tp, outp);
}